// Round 13
// baseline (179.472 us; speedup 1.0000x reference)
//
#include <hip/hip_runtime.h>
#include <stdint.h>

// S=8, N=4096, F_IN=F_OUT=128
constexpr int N  = 4096;
constexpr int F  = 128;
constexpr int S  = 8;
constexpr int BM = 16;              // rows per WAVE
constexpr int KSPLIT = 4;
constexpr int KRANGE = N / KSPLIT;  // 1024
constexpr int BK = 32;              // k-chunk
constexpr int NCH = KRANGE / BK;    // 32 chunks per wave
constexpr int NT = 256;             // 4 autonomous waves per block

typedef float f4  __attribute__((ext_vector_type(4)));
typedef short bf16x8 __attribute__((ext_vector_type(8)));
typedef unsigned short us4 __attribute__((ext_vector_type(4)));
typedef unsigned short us8 __attribute__((ext_vector_type(8)));

__device__ __forceinline__ unsigned short f2bf(float f) {
  union { float f; unsigned int u; } v; v.f = f;
  unsigned int u = v.u + 0x7FFFu + ((v.u >> 16) & 1u);  // RNE
  return (unsigned short)(u >> 16);
}

__device__ __forceinline__ void bar_sync() {
  asm volatile("s_waitcnt lgkmcnt(0)" ::: "memory");
  __builtin_amdgcn_s_barrier();
  asm volatile("" ::: "memory");
}

// async global->LDS, 16B/lane; LDS dest = wave-uniform base + lane*16.
__device__ __forceinline__ void gload_lds16(const void* g, void* l) {
  __builtin_amdgcn_global_load_lds(
      (const __attribute__((address_space(1))) void*)g,
      (__attribute__((address_space(3))) void*)l, 16, 0, 0);
}

// ---------------- kernel 0: xT[f][k] = bf16(x[k][f]) ----------------
__global__ __launch_bounds__(256, 2) void ggd_xt(
    const float* __restrict__ x, unsigned short* __restrict__ xT) {
  __shared__ float xl[64][132];
  const int t  = threadIdx.x;
  const int k0 = blockIdx.x * 64;
  {
    const int kr = t >> 2, fs = (t & 3) * 32;
    const float* src = x + (size_t)(k0 + kr) * F + fs;
#pragma unroll
    for (int i = 0; i < 8; ++i)
      *(f4*)&xl[kr][fs + i * 4] = *(const f4*)(src + i * 4);
  }
  __syncthreads();
  {
    const int f = t >> 1, kh = (t & 1) * 32;
    us4 o[8];
#pragma unroll
    for (int i = 0; i < 32; ++i)
      o[i >> 2][i & 3] = f2bf(xl[kh + i][f]);
    unsigned short* dst = xT + (size_t)f * N + k0 + kh;
#pragma unroll
    for (int j = 0; j < 8; ++j)
      *(us4*)(dst + j * 4) = o[j];
  }
}

// ------ kernel 1: wave-autonomous diffuse (ZERO barriers) ------
// Each wave independently: stage T chunk -> wave-private LDS (counted
// vmcnt), build its MFMA A-fragment in registers (q never hits LDS),
// MFMA against register B-fragments from L2-hot xT. No __syncthreads.
__global__ __launch_bounds__(NT, 1) void ggd_wave(
    const float* __restrict__ theta,
    const float* __restrict__ Ts,     // [S][N][N]
    const unsigned short* __restrict__ xT,  // [F][N] bf16
    const float* __restrict__ a,      // [N][N]
    float* __restrict__ parts)        // [KSPLIT][N][F]
{
  // 4 waves x 2 bufs x 8 slices x [16][32] f32 = 128 KB, wave-private slots
  __shared__ float rawT[4][2][S][BM][BK];

  const int t    = threadIdx.x;
  const int wave = t >> 6, lane = t & 63;
  const int wid  = blockIdx.x * 4 + wave;
  const int rb   = wid >> 2;          // 0..255
  const int ks   = wid & 3;           // 0..3
  const int n0   = rb * BM;
  const int k0   = ks * KRANGE;
  const size_t slice = (size_t)N * N;

  float th[S];
#pragma unroll
  for (int s = 0; s < S; ++s) th[s] = theta[s];

  // MFMA lane geometry (validated in R8-R12):
  // A[row=lane&15][k = 8*(lane>>4)+j]; C/D row=(lane>>4)*4+reg, col=lane&15
  const int r   = lane & 15;
  const int kb  = 8 * (lane >> 4);    // float k-offset
  const int kb4 = 2 * (lane >> 4);    // f4 k-offset
  const int rs  = r & 7;              // read-side swizzle key

  // staging lane geometry: instr = (slice s, row-half h); lane covers
  // row h*8 + (lane>>3), src f4 slot pre-swizzled so that
  // LDS[r][k4] = T[r][k4 ^ (r&7)]  (rule #21: linear dest, swizzled src)
  const int g_row = lane >> 3;               // 0..7 (== row&7 for both h)
  const int g_k4  = (lane & 7) ^ g_row;      // swizzled source f4

  auto stage = [&](int c, int buf) {
    const size_t col = (size_t)(k0 + c * BK) + 4 * g_k4;
    float* dst0 = &rawT[wave][buf][0][0][0];
#pragma unroll
    for (int j = 0; j < 16; ++j) {
      const int s = j >> 1, h = j & 1;
      const float* src = Ts + (size_t)s * slice +
                         (size_t)(n0 + h * 8 + g_row) * N + col;
      gload_lds16(src, dst0 + (size_t)s * (BM * BK) + h * 8 * BK);
    }
  };

  f4 acc[8];
#pragma unroll
  for (int i = 0; i < 8; ++i) acc[i] = (f4)(0.f);

  // prologue: chunk 0 in flight
  stage(0, 0);

  for (int c = 0; c < NCH; ++c) {
    const int kc = k0 + c * BK;

    // B(c) + a(c) BEFORE stage(c+1): older vmcnt position, so the single
    // counted wait below retires them together with chunk c's T.
    bf16x8 B[8];
#pragma unroll
    for (int i = 0; i < 8; ++i)
      B[i] = *(const bf16x8*)(xT + (size_t)(i * 16 + r) * N + kc + kb);
    f4 av0 = *(const f4*)(a + (size_t)(n0 + r) * N + kc + kb);
    f4 av1 = *(const f4*)(a + (size_t)(n0 + r) * N + kc + kb + 4);
    asm volatile("" ::: "memory");     // pin issue order

    if (c + 1 < NCH) {
      stage(c + 1, (c + 1) & 1);       // 16 gloads, stay in flight
      asm volatile("s_waitcnt vmcnt(16)" ::: "memory");  // T(c),B,a landed
    } else {
      asm volatile("s_waitcnt vmcnt(0)" ::: "memory");
    }

    // ---- qgen: A-fragment entirely in registers ----
    const float* base = &rawT[wave][c & 1][0][r][0];
    f4 s0 = (f4)(0.f), s1 = (f4)(0.f);
#pragma unroll
    for (int s = 0; s < S; ++s) {
      const float* bs = base + (size_t)s * (BM * BK);
      f4 t0 = *(const f4*)(bs + 4 * ((kb4 + 0) ^ rs));
      f4 t1 = *(const f4*)(bs + 4 * ((kb4 + 1) ^ rs));
#pragma unroll
      for (int e = 0; e < 4; ++e) {
        s0[e] = fmaf(th[s], t0[e], s0[e]);
        s1[e] = fmaf(th[s], t1[e], s1[e]);
      }
    }
    us8 u;
#pragma unroll
    for (int e = 0; e < 4; ++e) {
      u[e]     = f2bf(av0[e] * s0[e]);
      u[4 + e] = f2bf(av1[e] * s1[e]);
    }
    bf16x8 af = *(bf16x8*)&u;

#pragma unroll
    for (int i = 0; i < 8; ++i)
      acc[i] = __builtin_amdgcn_mfma_f32_16x16x32_bf16(af, B[i], acc[i],
                                                       0, 0, 0);
  }

  // ---- partials: C/D row=(lane>>4)*4+rr, col=lane&15 ----
  const int crow = n0 + (lane >> 4) * 4;
#pragma unroll
  for (int i = 0; i < 8; ++i) {
    const int fo = i * 16 + r;
#pragma unroll
    for (int rr = 0; rr < 4; ++rr)
      parts[((size_t)ks * N + crow + rr) * F + fo] = acc[i][rr];
  }
}

// ---------------- kernel 2: reduce + PReLU + FC ----------------
__global__ __launch_bounds__(256, 2) void ggd_fc(
    const float* __restrict__ W,      // [F][F] row-major [fo][fi]
    const float* __restrict__ bfc,    // [F]
    const float* __restrict__ alpha,  // [F]
    const float* __restrict__ src,    // parts [KSPLIT][N][F]
    float* __restrict__ out)          // [N][F]
{
  __shared__ float p_lds[16 * F];     // 8 KB
  const int t  = threadIdx.x;
  const int n0 = blockIdx.x * 16;

  {
    const int lr = t >> 4, c8 = (t & 15) * 8;
    f4 v0 = (f4)(0.f), v1 = (f4)(0.f);
#pragma unroll
    for (int ks = 0; ks < KSPLIT; ++ks) {
      const float* sp = src + ((size_t)ks * N + n0 + lr) * F + c8;
      v0 += *(const f4*)(sp);
      v1 += *(const f4*)(sp + 4);
    }
    f4 a0 = *(const f4*)(alpha + c8);
    f4 a1 = *(const f4*)(alpha + c8 + 4);
#pragma unroll
    for (int j = 0; j < 4; ++j) {
      v0[j] = v0[j] >= 0.f ? v0[j] : a0[j] * v0[j];
      v1[j] = v1[j] >= 0.f ? v1[j] : a1[j] * v1[j];
    }
    *(f4*)&p_lds[lr * F + c8]     = v0;
    *(f4*)&p_lds[lr * F + c8 + 4] = v1;
  }
  __syncthreads();

  const int r2  = t >> 5;             // 0..7
  const int fo0 = (t & 31) * 4;
  f4 accA = *(const f4*)(bfc + fo0);
  f4 accB = accA;
#pragma unroll 4
  for (int fi4 = 0; fi4 < F / 4; ++fi4) {
    f4 pA = *(const f4*)&p_lds[r2 * F + fi4 * 4];
    f4 pB = *(const f4*)&p_lds[(r2 + 8) * F + fi4 * 4];
#pragma unroll
    for (int e = 0; e < 4; ++e) {
      f4 wv = *(const f4*)(W + (size_t)(fo0 + e) * F + fi4 * 4);
      accA[e] = fmaf(pA[0], wv[0], fmaf(pA[1], wv[1],
                fmaf(pA[2], wv[2], fmaf(pA[3], wv[3], accA[e]))));
      accB[e] = fmaf(pB[0], wv[0], fmaf(pB[1], wv[1],
                fmaf(pB[2], wv[2], fmaf(pB[3], wv[3], accB[e]))));
    }
  }
  *(f4*)(out + (size_t)(n0 + r2) * F + fo0)     = accA;
  *(f4*)(out + (size_t)(n0 + r2 + 8) * F + fo0) = accB;
}

// -------- fallback (ws too small): round-1 fused kernel --------
__global__ __launch_bounds__(256, 1) void ggd_fused_fb(
    const float* __restrict__ theta, const float* __restrict__ Ts,
    const float* __restrict__ x, const float* __restrict__ a,
    const float* __restrict__ W, const float* __restrict__ bfc,
    const float* __restrict__ alpha, float* __restrict__ out) {
  constexpr int BMf = 16, BKf = 64, NCF = N / BKf;
  __shared__ float q_l[2][BMf][BKf];
  __shared__ float p_l[BMf][F];
  const int t  = threadIdx.x;
  const int n0 = blockIdx.x * BMf;
  float th[S];
#pragma unroll
  for (int s = 0; s < S; ++s) th[s] = theta[s];
  const int qr = t >> 4, qk = (t & 15) << 2;
  const size_t rowOff = (size_t)(n0 + qr) * N, sliceSz = (size_t)N * N;
  const int tx = t & 31, ty = t >> 5;
  const int r0 = ty * 2, r1 = r0 + 1;
  f4 acc0 = (f4)(0.f), acc1 = (f4)(0.f);
  f4 tv[S]; f4 avv;
  auto loadc = [&](int c) {
    const size_t off = rowOff + (size_t)c * BKf + qk;
    avv = *(const f4*)(a + off);
#pragma unroll
    for (int s = 0; s < S; ++s)
      tv[s] = *(const f4*)(Ts + (size_t)s * sliceSz + off);
  };
  auto qstore = [&](int buf) {
    f4 qv;
#pragma unroll
    for (int j = 0; j < 4; ++j) {
      float sum = th[0] * tv[0][j];
#pragma unroll
      for (int s = 1; s < S; ++s) sum = fmaf(th[s], tv[s][j], sum);
      qv[j] = avv[j] * sum;
    }
    *(f4*)&q_l[buf][qr][qk] = qv;
  };
  loadc(0); qstore(0);
  for (int c = 0; c < NCF; ++c) {
    const int buf = c & 1;
    if (c + 1 < NCF) loadc(c + 1);
    bar_sync();
    const float* xp = x + (size_t)c * BKf * F + tx * 4;
#pragma unroll 4
    for (int kk4 = 0; kk4 < BKf / 4; ++kk4) {
      f4 q0 = *(const f4*)&q_l[buf][r0][kk4 * 4];
      f4 q1 = *(const f4*)&q_l[buf][r1][kk4 * 4];
#pragma unroll
      for (int j = 0; j < 4; ++j) {
        f4 xv = *(const f4*)(xp + (size_t)(kk4 * 4 + j) * F);
#pragma unroll
        for (int e = 0; e < 4; ++e) {
          acc0[e] = fmaf(q0[j], xv[e], acc0[e]);
          acc1[e] = fmaf(q1[j], xv[e], acc1[e]);
        }
      }
    }
    if (c + 1 < NCF) qstore(buf ^ 1);
  }
  {
    f4 al = *(const f4*)(alpha + tx * 4);
#pragma unroll
    for (int j = 0; j < 4; ++j) {
      acc0[j] = acc0[j] >= 0.f ? acc0[j] : al[j] * acc0[j];
      acc1[j] = acc1[j] >= 0.f ? acc1[j] : al[j] * acc1[j];
    }
  }
  *(f4*)&p_l[r0][tx * 4] = acc0;
  *(f4*)&p_l[r1][tx * 4] = acc1;
  bar_sync();
  const int rr = t >> 4, fo0 = (t & 15) * 8;
  float accF[8];
  {
    f4 b0 = *(const f4*)(bfc + fo0);
    f4 b1 = *(const f4*)(bfc + fo0 + 4);
#pragma unroll
    for (int j = 0; j < 4; ++j) { accF[j] = b0[j]; accF[4 + j] = b1[j]; }
  }
#pragma unroll 8
  for (int fi4 = 0; fi4 < F / 4; ++fi4) {
    f4 p4 = *(const f4*)&p_l[rr][fi4 * 4];
#pragma unroll
    for (int j = 0; j < 8; ++j) {
      f4 w4 = *(const f4*)(W + (size_t)(fo0 + j) * F + fi4 * 4);
      accF[j] = fmaf(p4[0], w4[0], fmaf(p4[1], w4[1],
                fmaf(p4[2], w4[2], fmaf(p4[3], w4[3], accF[j]))));
    }
  }
  f4 o0, o1;
#pragma unroll
  for (int j = 0; j < 4; ++j) { o0[j] = accF[j]; o1[j] = accF[4 + j]; }
  float* op = out + (size_t)(n0 + rr) * F + fo0;
  *(f4*)op       = o0;
  *(f4*)(op + 4) = o1;
}

extern "C" void kernel_launch(void* const* d_in, const int* in_sizes, int n_in,
                              void* d_out, int out_size, void* d_ws, size_t ws_size,
                              hipStream_t stream) {
  const float* theta = (const float*)d_in[0];
  const float* Ts    = (const float*)d_in[1];
  const float* x     = (const float*)d_in[2];
  const float* a     = (const float*)d_in[3];
  const float* W     = (const float*)d_in[4];
  const float* bfc   = (const float*)d_in[5];
  const float* alpha = (const float*)d_in[6];
  float* out = (float*)d_out;

  const size_t part_bytes = (size_t)KSPLIT * N * F * sizeof(float);  // 8.4 MB
  const size_t xt_bytes   = (size_t)N * F * 2;                       // 1 MB
  if (ws_size >= part_bytes + xt_bytes && d_ws != nullptr) {
    float* parts = (float*)d_ws;
    unsigned short* xT = (unsigned short*)((char*)d_ws + part_bytes);
    ggd_xt  <<<dim3(N / 64), dim3(256), 0, stream>>>(x, xT);
    ggd_wave<<<dim3((N / BM) * KSPLIT / 4), dim3(NT), 0, stream>>>(
        theta, Ts, xT, a, parts);
    ggd_fc  <<<dim3(N / 16), dim3(256), 0, stream>>>(
        W, bfc, alpha, parts, out);
  } else {
    ggd_fused_fb<<<dim3(N / 16), dim3(256), 0, stream>>>(
        theta, Ts, x, a, W, bfc, alpha, out);
  }
}

// Round 14
// 173.647 us; speedup vs baseline: 1.0335x; 1.0335x over previous
//
#include <hip/hip_runtime.h>
#include <stdint.h>

// S=8, N=4096, F_IN=F_OUT=128
constexpr int N  = 4096;
constexpr int F  = 128;
constexpr int S  = 8;
constexpr int BM = 16;              // rows per block
constexpr int KSPLIT = 4;
constexpr int KRANGE = N / KSPLIT;  // 1024
constexpr int BK = 32;              // k-chunk
constexpr int NCH = KRANGE / BK;    // 32 chunks per block (even)
constexpr int NT = 256;             // 4 waves

typedef float f4  __attribute__((ext_vector_type(4)));
typedef float f2  __attribute__((ext_vector_type(2)));
typedef short bf16x8 __attribute__((ext_vector_type(8)));
typedef unsigned short us4 __attribute__((ext_vector_type(4)));

__device__ __forceinline__ unsigned short f2bf(float f) {
  union { float f; unsigned int u; } v; v.f = f;
  unsigned int u = v.u + 0x7FFFu + ((v.u >> 16) & 1u);  // RNE
  return (unsigned short)(u >> 16);
}

// Barrier that waits only on LDS ops.
__device__ __forceinline__ void bar_sync() {
  asm volatile("s_waitcnt lgkmcnt(0)" ::: "memory");
  __builtin_amdgcn_s_barrier();
  asm volatile("" ::: "memory");
}
__device__ __forceinline__ void vm_drain() {
  asm volatile("s_waitcnt vmcnt(0)" ::: "memory");
}
// steady state: one iteration issues exactly 19 VMEM ops (16 stage + 2 B + 1 a)
__device__ __forceinline__ void vm_wait19() {
  asm volatile("s_waitcnt vmcnt(19)" ::: "memory");
}
// tail iteration issues only 2 (B-frags)
__device__ __forceinline__ void vm_wait2() {
  asm volatile("s_waitcnt vmcnt(2)" ::: "memory");
}

// async global->LDS, 16B/lane; LDS dest = wave-uniform base + lane*16.
__device__ __forceinline__ void gload_lds16(const void* g, void* l) {
  __builtin_amdgcn_global_load_lds(
      (const __attribute__((address_space(1))) void*)g,
      (__attribute__((address_space(3))) void*)l, 16, 0, 0);
}

// ---------------- kernel 0: xT[f][k] = bf16(x[k][f]) ----------------
__global__ __launch_bounds__(256, 2) void ggd_xt(
    const float* __restrict__ x, unsigned short* __restrict__ xT) {
  __shared__ float xl[64][132];
  const int t  = threadIdx.x;
  const int k0 = blockIdx.x * 64;
  {
    const int kr = t >> 2, fs = (t & 3) * 32;
    const float* src = x + (size_t)(k0 + kr) * F + fs;
#pragma unroll
    for (int i = 0; i < 8; ++i)
      *(f4*)&xl[kr][fs + i * 4] = *(const f4*)(src + i * 4);
  }
  __syncthreads();
  {
    const int f = t >> 1, kh = (t & 1) * 32;
    us4 o[8];
#pragma unroll
    for (int i = 0; i < 32; ++i)
      o[i >> 2][i & 3] = f2bf(xl[kh + i][f]);
    unsigned short* dst = xT + (size_t)f * N + k0 + kh;
#pragma unroll
    for (int j = 0; j < 8; ++j)
      *(us4*)(dst + j * 4) = o[j];
  }
}

// ---- kernel 1: q-gen + MFMA q@x partials; 16 waves/CU, depth-2 vmcnt ----
__global__ __launch_bounds__(NT, 4) void ggd_diffuse(
    const float* __restrict__ theta,
    const float* __restrict__ Ts,     // [S][N][N]
    const unsigned short* __restrict__ xT,  // [F][N] bf16
    const float* __restrict__ a,      // [N][N]
    float* __restrict__ parts)        // [KSPLIT][N][F]
{
  __shared__ float rawT[2][S][BM][BK];        // 32 KB double-buffered
  __shared__ unsigned short q_lds[2][BM][BK]; //  2 KB double-buffered (bf16)

  const int t  = threadIdx.x;
  const int rb = blockIdx.x >> 2;     // 0..255 row block
  const int ks = blockIdx.x & 3;      // 0..3 k-split
  const int n0 = rb * BM;
  const int k0 = ks * KRANGE;

  float th[S];
#pragma unroll
  for (int s = 0; s < S; ++s) th[s] = theta[s];

  const int wave = t >> 6, lane = t & 63;
  const size_t slice = (size_t)N * N;

  // qgen/a mapping: thread t -> row t>>4 (0..15), cols (t&15)*2..+1
  const int qr = t >> 4;
  const int qk = (t & 15) * 2;

  f4 acc[2];
#pragma unroll
  for (int i = 0; i < 2; ++i) acc[i] = (f4)(0.f);

  // rawT: 16 KB/chunk = 16 x 1KB instrs (4/wave); instr i: slice i>>1,
  // rows (i&1)*8..+7; lane covers row lane>>3, float cols (lane&7)*4..+3
  auto stage_rawT = [&](int c, int buf) {
    const size_t cb = (size_t)(k0 + c * BK) + (lane & 7) * 4;
    const int grow = lane >> 3;
#pragma unroll
    for (int j = 0; j < 4; ++j) {
      const int i = wave * 4 + j;     // 0..15
      const int s  = i >> 1;
      const int rh = (i & 1) * 8;
      const float* src = Ts + (size_t)s * slice +
                         (size_t)(n0 + rh + grow) * N + cb;
      gload_lds16(src, &rawT[buf][s][rh][0]);
    }
  };

  // B-fragments for chunk c from L2-hot xT: wave w -> f-tiles {2w, 2w+1}
  auto bfrag_load = [&](int c, bf16x8* B) {
    const int kc = k0 + c * BK;
#pragma unroll
    for (int i = 0; i < 2; ++i) {
      const int fr = (wave * 2 + i) * 16 + (lane & 15);
      B[i] = *(const bf16x8*)(xT + (size_t)fr * N + kc + (lane >> 4) * 8);
    }
  };

  auto load_a = [&](int c) -> f2 {
    return *(const f2*)(a + (size_t)(n0 + qr) * N + (k0 + c * BK + qk));
  };

  // q[c1&1][qr][qk..+1] = bf16( a * sum_s th[s]*T[s] ), from rawT[c1&1]
  auto qgen = [&](int c1, f2 av) {
    const float* rt = &rawT[c1 & 1][0][qr][qk];
    f2 sum;
    {
      f2 tv = *(const f2*)(rt);
      sum[0] = th[0] * tv[0];
      sum[1] = th[0] * tv[1];
    }
#pragma unroll
    for (int s = 1; s < S; ++s) {
      f2 tv = *(const f2*)(rt + (size_t)s * (BM * BK));
      sum[0] = fmaf(th[s], tv[0], sum[0]);
      sum[1] = fmaf(th[s], tv[1], sum[1]);
    }
    const unsigned int packed =
        (unsigned int)f2bf(av[0] * sum[0]) |
        ((unsigned int)f2bf(av[1] * sum[1]) << 16);
    *(unsigned int*)&q_lds[c1 & 1][qr][qk] = packed;
  };

  // 2 MFMA: A = q tile (one 16x16x32 step), B = register fragments
  auto compute = [&](int c, const bf16x8* B) {
    const unsigned short* qb = &q_lds[c & 1][0][0];
    bf16x8 af = *(const bf16x8*)(qb + (lane & 15) * BK + (lane >> 4) * 8);
    acc[0] = __builtin_amdgcn_mfma_f32_16x16x32_bf16(af, B[0], acc[0], 0, 0, 0);
    acc[1] = __builtin_amdgcn_mfma_f32_16x16x32_bf16(af, B[1], acc[1], 0, 0, 0);
  };

  f2 avE, avO;
  bf16x8 bE[2], bO[2];

  // ---- prologue: chunks 0,1 staged; B(0); a(0),a(1) ----
  stage_rawT(0, 0);
  stage_rawT(1, 1);
  bfrag_load(0, bE);
  avE = load_a(0);
  avO = load_a(1);
  vm_drain();
  bar_sync();
  qgen(0, avE);
  bar_sync();

  // ---- steady state: depth-2, wait-own-then-barrier (race-free) ----
  for (int cc = 0; cc + 1 < NCH - 2; cc += 2) {
    {
      const int c = cc;                 // even
      stage_rawT(c + 2, c & 1);
      bfrag_load(c + 1, bO);
      avE = load_a(c + 2);
      compute(c, bE);                   // q_lds[c&1] + bE (reg dep)
      vm_wait19();                      // my iter-(c-1) loads landed
      bar_sync();                       // all waves' rawT(c+1) landed
      qgen(c + 1, avO);
      bar_sync();                       // publish q[(c+1)&1]
    }
    {
      const int c = cc + 1;             // odd
      stage_rawT(c + 2, c & 1);
      bfrag_load(c + 1, bE);
      avO = load_a(c + 2);
      compute(c, bO);
      vm_wait19();
      bar_sync();
      qgen(c + 1, avE);
      bar_sync();
    }
  }

  // ---- tail: c = NCH-2 (even), NCH-1 ----
  {
    const int c = NCH - 2;
    bfrag_load(c + 1, bO);
    compute(c, bE);
    vm_wait2();                         // prior iteration's 19 landed
    bar_sync();
    qgen(c + 1, avO);
    bar_sync();
  }
  compute(NCH - 1, bO);

  // ---- partials; C/D: col=lane&15, row=(lane>>4)*4+reg ----
  const int crow = n0 + (lane >> 4) * 4;
  const int ccol = lane & 15;
#pragma unroll
  for (int i = 0; i < 2; ++i) {
    const int fo = (wave * 2 + i) * 16 + ccol;
#pragma unroll
    for (int r = 0; r < 4; ++r)
      parts[((size_t)ks * N + crow + r) * F + fo] = acc[i][r];
  }
}

// ---------------- kernel 2: reduce + PReLU + FC ----------------
__global__ __launch_bounds__(256, 2) void ggd_fc(
    const float* __restrict__ W,      // [F][F] row-major [fo][fi]
    const float* __restrict__ bfc,    // [F]
    const float* __restrict__ alpha,  // [F]
    const float* __restrict__ src,    // parts [KSPLIT][N][F]
    float* __restrict__ out)          // [N][F]
{
  __shared__ float p_lds[16 * F];     // 8 KB
  const int t  = threadIdx.x;
  const int n0 = blockIdx.x * 16;

  {
    const int lr = t >> 4, c8 = (t & 15) * 8;
    f4 v0 = (f4)(0.f), v1 = (f4)(0.f);
#pragma unroll
    for (int ks = 0; ks < KSPLIT; ++ks) {
      const float* sp = src + ((size_t)ks * N + n0 + lr) * F + c8;
      v0 += *(const f4*)(sp);
      v1 += *(const f4*)(sp + 4);
    }
    f4 a0 = *(const f4*)(alpha + c8);
    f4 a1 = *(const f4*)(alpha + c8 + 4);
#pragma unroll
    for (int j = 0; j < 4; ++j) {
      v0[j] = v0[j] >= 0.f ? v0[j] : a0[j] * v0[j];
      v1[j] = v1[j] >= 0.f ? v1[j] : a1[j] * v1[j];
    }
    *(f4*)&p_lds[lr * F + c8]     = v0;
    *(f4*)&p_lds[lr * F + c8 + 4] = v1;
  }
  __syncthreads();

  const int r2  = t >> 5;             // 0..7
  const int fo0 = (t & 31) * 4;
  f4 accA = *(const f4*)(bfc + fo0);
  f4 accB = accA;
#pragma unroll 4
  for (int fi4 = 0; fi4 < F / 4; ++fi4) {
    f4 pA = *(const f4*)&p_lds[r2 * F + fi4 * 4];
    f4 pB = *(const f4*)&p_lds[(r2 + 8) * F + fi4 * 4];
#pragma unroll
    for (int e = 0; e < 4; ++e) {
      f4 wv = *(const f4*)(W + (size_t)(fo0 + e) * F + fi4 * 4);
      accA[e] = fmaf(pA[0], wv[0], fmaf(pA[1], wv[1],
                fmaf(pA[2], wv[2], fmaf(pA[3], wv[3], accA[e]))));
      accB[e] = fmaf(pB[0], wv[0], fmaf(pB[1], wv[1],
                fmaf(pB[2], wv[2], fmaf(pB[3], wv[3], accB[e]))));
    }
  }
  *(f4*)(out + (size_t)(n0 + r2) * F + fo0)     = accA;
  *(f4*)(out + (size_t)(n0 + r2 + 8) * F + fo0) = accB;
}

// -------- fallback (ws too small): round-1 fused kernel --------
__global__ __launch_bounds__(256, 1) void ggd_fused_fb(
    const float* __restrict__ theta, const float* __restrict__ Ts,
    const float* __restrict__ x, const float* __restrict__ a,
    const float* __restrict__ W, const float* __restrict__ bfc,
    const float* __restrict__ alpha, float* __restrict__ out) {
  constexpr int BMf = 16, BKf = 64, NCF = N / BKf;
  __shared__ float q_l[2][BMf][BKf];
  __shared__ float p_l[BMf][F];
  const int t  = threadIdx.x;
  const int n0 = blockIdx.x * BMf;
  float th[S];
#pragma unroll
  for (int s = 0; s < S; ++s) th[s] = theta[s];
  const int qr = t >> 4, qk = (t & 15) << 2;
  const size_t rowOff = (size_t)(n0 + qr) * N, sliceSz = (size_t)N * N;
  const int tx = t & 31, ty = t >> 5;
  const int r0 = ty * 2, r1 = r0 + 1;
  f4 acc0 = (f4)(0.f), acc1 = (f4)(0.f);
  f4 tv[S]; f4 avv;
  auto loadc = [&](int c) {
    const size_t off = rowOff + (size_t)c * BKf + qk;
    avv = *(const f4*)(a + off);
#pragma unroll
    for (int s = 0; s < S; ++s)
      tv[s] = *(const f4*)(Ts + (size_t)s * sliceSz + off);
  };
  auto qstore = [&](int buf) {
    f4 qv;
#pragma unroll
    for (int j = 0; j < 4; ++j) {
      float sum = th[0] * tv[0][j];
#pragma unroll
      for (int s = 1; s < S; ++s) sum = fmaf(th[s], tv[s][j], sum);
      qv[j] = avv[j] * sum;
    }
    *(f4*)&q_l[buf][qr][qk] = qv;
  };
  loadc(0); qstore(0);
  for (int c = 0; c < NCF; ++c) {
    const int buf = c & 1;
    if (c + 1 < NCF) loadc(c + 1);
    bar_sync();
    const float* xp = x + (size_t)c * BKf * F + tx * 4;
#pragma unroll 4
    for (int kk4 = 0; kk4 < BKf / 4; ++kk4) {
      f4 q0 = *(const f4*)&q_l[buf][r0][kk4 * 4];
      f4 q1 = *(const f4*)&q_l[buf][r1][kk4 * 4];
#pragma unroll
      for (int j = 0; j < 4; ++j) {
        f4 xv = *(const f4*)(xp + (size_t)(kk4 * 4 + j) * F);
#pragma unroll
        for (int e = 0; e < 4; ++e) {
          acc0[e] = fmaf(q0[j], xv[e], acc0[e]);
          acc1[e] = fmaf(q1[j], xv[e], acc1[e]);
        }
      }
    }
    if (c + 1 < NCF) qstore(buf ^ 1);
  }
  {
    f4 al = *(const f4*)(alpha + tx * 4);
#pragma unroll
    for (int j = 0; j < 4; ++j) {
      acc0[j] = acc0[j] >= 0.f ? acc0[j] : al[j] * acc0[j];
      acc1[j] = acc1[j] >= 0.f ? acc1[j] : al[j] * acc1[j];
    }
  }
  *(f4*)&p_l[r0][tx * 4] = acc0;
  *(f4*)&p_l[r1][tx * 4] = acc1;
  bar_sync();
  const int rr = t >> 4, fo0 = (t & 15) * 8;
  float accF[8];
  {
    f4 b0 = *(const f4*)(bfc + fo0);
    f4 b1 = *(const f4*)(bfc + fo0 + 4);
#pragma unroll
    for (int j = 0; j < 4; ++j) { accF[j] = b0[j]; accF[4 + j] = b1[j]; }
  }
#pragma unroll 8
  for (int fi4 = 0; fi4 < F / 4; ++fi4) {
    f4 p4 = *(const f4*)&p_l[rr][fi4 * 4];
#pragma unroll
    for (int j = 0; j < 8; ++j) {
      f4 w4 = *(const f4*)(W + (size_t)(fo0 + j) * F + fi4 * 4);
      accF[j] = fmaf(p4[0], w4[0], fmaf(p4[1], w4[1],
                fmaf(p4[2], w4[2], fmaf(p4[3], w4[3], accF[j]))));
    }
  }
  f4 o0, o1;
#pragma unroll
  for (int j = 0; j < 4; ++j) { o0[j] = accF[j]; o1[j] = accF[4 + j]; }
  float* op = out + (size_t)(n0 + rr) * F + fo0;
  *(f4*)op       = o0;
  *(f4*)(op + 4) = o1;
}

extern "C" void kernel_launch(void* const* d_in, const int* in_sizes, int n_in,
                              void* d_out, int out_size, void* d_ws, size_t ws_size,
                              hipStream_t stream) {
  const float* theta = (const float*)d_in[0];
  const float* Ts    = (const float*)d_in[1];
  const float* x     = (const float*)d_in[2];
  const float* a     = (const float*)d_in[3];
  const float* W     = (const float*)d_in[4];
  const float* bfc   = (const float*)d_in[5];
  const float* alpha = (const float*)d_in[6];
  float* out = (float*)d_out;

  const size_t part_bytes = (size_t)KSPLIT * N * F * sizeof(float);  // 8.4 MB
  const size_t xt_bytes   = (size_t)N * F * 2;                       // 1 MB
  if (ws_size >= part_bytes + xt_bytes && d_ws != nullptr) {
    float* parts = (float*)d_ws;
    unsigned short* xT = (unsigned short*)((char*)d_ws + part_bytes);
    ggd_xt<<<dim3(N / 64), dim3(256), 0, stream>>>(x, xT);
    ggd_diffuse<<<dim3((N / BM) * KSPLIT), dim3(NT), 0, stream>>>(
        theta, Ts, xT, a, parts);
    ggd_fc<<<dim3(N / 16), dim3(256), 0, stream>>>(
        W, bfc, alpha, parts, out);
  } else {
    ggd_fused_fb<<<dim3(N / 16), dim3(256), 0, stream>>>(
        theta, Ts, x, a, W, bfc, alpha, out);
  }
}